// Round 1
// baseline (544.622 us; speedup 1.0000x reference)
//
#include <hip/hip_runtime.h>

typedef float v2f __attribute__((ext_vector_type(2)));

namespace {
constexpr int D = 4096;            // d_model
constexpr int E = 64;              // n_experts
constexpr int M = 16384;           // B*S
constexpr int BM = 128;            // rows per block
constexpr int BK = 32;             // k-tile
constexpr int KSPLIT = 4;
constexpr int KC = D / KSPLIT;     // 1024 k per block
constexpr int NT = KC / BK;        // 32 tiles
constexpr int ROWBLOCKS = M / BM;  // 128

// output layout (floats, concatenated in reference return order)
constexpr int OFF_IDX = 0;                 // [M][2] as float
constexpr int OFF_SCORES = 32768;          // [M][2]
constexpr int OFF_PROBS = 65536;           // [M][64]
constexpr int OFF_Z = 1114112;             // scalar
constexpr int OFF_IMP = 1114113;           // [64]
constexpr int OFF_LOAD = 1114177;          // [64]
}  // namespace

// ---------------------------------------------------------------------------
// Kernel 1: fp32 GEMM  logits[M][64] += x[M][4096] . W[64][4096]^T
// K-split 4 for occupancy (512 blocks). Register tile 8 rows x 4 experts.
// float2 math to coax v_pk_fma_f32 out of the backend.
// ---------------------------------------------------------------------------
__global__ __launch_bounds__(256, 2) void router_gemm(
    const float* __restrict__ xg, const float* __restrict__ wg,
    float* __restrict__ logits) {
  __shared__ __align__(16) float xs[BK][BM + 4];  // transposed x tile, 16B-aligned stride
  __shared__ __align__(16) float wsm[BK][E];      // transposed W tile

  const int t = threadIdx.x;
  const int bm = blockIdx.x & (ROWBLOCKS - 1);
  const int sp = blockIdx.x >> 7;  // / ROWBLOCKS
  const int row0 = bm * BM;
  const int k0 = sp * KC;

  const int tx = t & 15;  // expert group (4 experts)
  const int ty = t >> 4;  // row group (8 rows)

  // global staging indices: 8 lanes x 16B cover one row-chunk of 32 floats
  const int lrow = t >> 3;       // 0..31
  const int lcol = (t & 7) * 4;  // 0..28

  const float* xp = xg + (size_t)(row0 + lrow) * D + k0 + lcol;
  const float* wp = wg + (size_t)lrow * D + k0 + lcol;

  float4 xa[4];
  float4 wa[2];

  auto load_tile = [&](int kt) {
#pragma unroll
    for (int i = 0; i < 4; ++i)
      xa[i] = *(const float4*)(xp + (size_t)(i * 32) * D + kt);
#pragma unroll
    for (int i = 0; i < 2; ++i)
      wa[i] = *(const float4*)(wp + (size_t)(i * 32) * D + kt);
  };

  v2f acc[4][4];
#pragma unroll
  for (int i = 0; i < 4; ++i)
#pragma unroll
    for (int j = 0; j < 4; ++j) acc[i][j] = (v2f){0.f, 0.f};

  load_tile(0);
  for (int tile = 0; tile < NT; ++tile) {
    __syncthreads();
    // scatter staged regs into transposed LDS tiles
#pragma unroll
    for (int i = 0; i < 4; ++i) {
      const int r = lrow + i * 32;
      xs[lcol + 0][r] = xa[i].x;
      xs[lcol + 1][r] = xa[i].y;
      xs[lcol + 2][r] = xa[i].z;
      xs[lcol + 3][r] = xa[i].w;
    }
#pragma unroll
    for (int i = 0; i < 2; ++i) {
      const int e = lrow + i * 32;
      wsm[lcol + 0][e] = wa[i].x;
      wsm[lcol + 1][e] = wa[i].y;
      wsm[lcol + 2][e] = wa[i].z;
      wsm[lcol + 3][e] = wa[i].w;
    }
    __syncthreads();
    if (tile + 1 < NT) load_tile((tile + 1) * BK);  // prefetch overlaps compute
#pragma unroll
    for (int k = 0; k < BK; ++k) {
      const float4 a0 = *(const float4*)&xs[k][ty * 8];
      const float4 a1 = *(const float4*)&xs[k][ty * 8 + 4];
      const float4 b = *(const float4*)&wsm[k][tx * 4];
      v2f a2[4];
      a2[0] = (v2f){a0.x, a0.y};
      a2[1] = (v2f){a0.z, a0.w};
      a2[2] = (v2f){a1.x, a1.y};
      a2[3] = (v2f){a1.z, a1.w};
      const float bb[4] = {b.x, b.y, b.z, b.w};
#pragma unroll
      for (int i = 0; i < 4; ++i)
#pragma unroll
        for (int j = 0; j < 4; ++j) {
          const v2f bv = {bb[j], bb[j]};
          acc[i][j] = __builtin_elementwise_fma(a2[i], bv, acc[i][j]);
        }
    }
  }

  // accumulate K-split partials (4 contributions per address, fp32 atomics)
#pragma unroll
  for (int i = 0; i < 4; ++i) {
    const int r = row0 + ty * 8 + 2 * i;
#pragma unroll
    for (int j = 0; j < 4; ++j) {
      const int e = tx * 4 + j;
      atomicAdd(&logits[(size_t)r * E + e], acc[i][j].x);
      atomicAdd(&logits[(size_t)(r + 1) * E + e], acc[i][j].y);
    }
  }
}

// ---------------------------------------------------------------------------
// Kernel 2: per-row softmax / top-2 / logsumexp + global stats.
// lane == expert (E == wavefront size). One wave handles 64 rows.
// ---------------------------------------------------------------------------
__global__ __launch_bounds__(256) void router_epilogue(
    const float* __restrict__ logits, float* __restrict__ out) {
  const int t = threadIdx.x;
  const int lane = t & 63;
  const int w = t >> 6;
  const int gw = blockIdx.x * 4 + w;  // 0..255 global wave id

  __shared__ float imp_sh[4][64];
  __shared__ float z2_sh[4];
  __shared__ int cnt_sh[64];

  if (t < 64) cnt_sh[t] = 0;
  __syncthreads();

  float imp_acc = 0.f;
  float z2_acc = 0.f;

  const int r0 = gw * 64;
  for (int r = r0; r < r0 + 64; ++r) {
    const float l = logits[(size_t)r * 64 + lane];

    // logsumexp
    float m = l;
#pragma unroll
    for (int off = 32; off > 0; off >>= 1) m = fmaxf(m, __shfl_xor(m, off));
    const float ex = __expf(l - m);
    float s = ex;
#pragma unroll
    for (int off = 32; off > 0; off >>= 1) s += __shfl_xor(s, off);
    const float z = m + __logf(s);

    // full softmax
    const float p = __expf(l - z);
    out[OFF_PROBS + (size_t)r * 64 + lane] = p;
    imp_acc += p;
    z2_acc += z * z;  // identical on all lanes; lane 0's copy is used

    // top-1 (lower index wins ties, matching lax.top_k)
    float v = l;
    int vi = lane;
#pragma unroll
    for (int off = 32; off > 0; off >>= 1) {
      const float ov = __shfl_xor(v, off);
      const int oi = __shfl_xor(vi, off);
      if (ov > v || (ov == v && oi < vi)) { v = ov; vi = oi; }
    }
    // top-2: mask out winner
    const float l2 = (lane == vi) ? -3.402823466e+38f : l;
    float v2 = l2;
    int vi2 = lane;
#pragma unroll
    for (int off = 32; off > 0; off >>= 1) {
      const float ov = __shfl_xor(v2, off);
      const int oi = __shfl_xor(vi2, off);
      if (ov > v2 || (ov == v2 && oi < vi2)) { v2 = ov; vi2 = oi; }
    }

    if (lane == 0) {
      out[OFF_IDX + 2 * r] = (float)vi;
      out[OFF_IDX + 2 * r + 1] = (float)vi2;
      const float e1 = __expf(v2 - v);  // v2 <= v, stable
      const float s0 = 1.f / (1.f + e1);
      out[OFF_SCORES + 2 * r] = s0;
      out[OFF_SCORES + 2 * r + 1] = e1 * s0;
      atomicAdd(&cnt_sh[vi], 1);
      atomicAdd(&cnt_sh[vi2], 1);
    }
  }

  imp_sh[w][lane] = imp_acc;
  if (lane == 0) z2_sh[w] = z2_acc;
  __syncthreads();

  if (t < 64) {
    const float si = imp_sh[0][t] + imp_sh[1][t] + imp_sh[2][t] + imp_sh[3][t];
    atomicAdd(&out[OFF_IMP + t], si * (1.f / 16384.f));
    // counts are integers; cnt/32768 and its partial sums are exactly
    // representable -> atomic order cannot change the result
    atomicAdd(&out[OFF_LOAD + t], (float)cnt_sh[t] * (1.f / 32768.f));
    if (t == 0)
      atomicAdd(&out[OFF_Z],
                (z2_sh[0] + z2_sh[1] + z2_sh[2] + z2_sh[3]) * (1.f / 16384.f));
  }
}

extern "C" void kernel_launch(void* const* d_in, const int* in_sizes, int n_in,
                              void* d_out, int out_size, void* d_ws, size_t ws_size,
                              hipStream_t stream) {
  const float* x = (const float*)d_in[0];
  const float* wgate = (const float*)d_in[1];
  float* out = (float*)d_out;
  float* logits = (float*)d_ws;  // 16384*64 fp32 = 4 MB scratch

  // zero the atomic-accumulated regions (ws + stats tail of d_out are poisoned)
  hipMemsetAsync(logits, 0, (size_t)M * E * sizeof(float), stream);
  hipMemsetAsync(out + OFF_Z, 0, 129 * sizeof(float), stream);

  router_gemm<<<dim3(ROWBLOCKS * KSPLIT), dim3(256), 0, stream>>>(x, wgate, logits);
  router_epilogue<<<dim3(64), dim3(256), 0, stream>>>(logits, out);
}

// Round 2
// 463.837 us; speedup vs baseline: 1.1742x; 1.1742x over previous
//
#include <hip/hip_runtime.h>

namespace {
constexpr int D = 4096;            // d_model
constexpr int E = 64;              // n_experts
constexpr int M = 16384;           // B*S
constexpr int BM = 128;            // rows per block
constexpr int BK = 32;             // k-tile
constexpr int KSPLIT = 8;
constexpr int KC = D / KSPLIT;     // 512 k per block
constexpr int NT = KC / BK;        // 16 tiles
constexpr int ROWBLOCKS = M / BM;  // 128

// output layout (floats, concatenated in reference return order)
constexpr int OFF_IDX = 0;                 // [M][2] as float
constexpr int OFF_SCORES = 32768;          // [M][2]
constexpr int OFF_PROBS = 65536;           // [M][64]
constexpr int OFF_Z = 1114112;             // scalar
constexpr int OFF_IMP = 1114113;           // [64]
constexpr int OFF_LOAD = 1114177;          // [64]
}  // namespace

// ---------------------------------------------------------------------------
// Kernel 1: fp32 GEMM  logits[M][64] += x[M][4096] . W[64][4096]^T
// KSPLIT=8 -> 1024 blocks -> 4 blocks/CU (grid was the occupancy cap at 2).
// Register tile 8 rows x 4 experts; explicit k+1 fragment prefetch for ILP.
// ---------------------------------------------------------------------------
__global__ __launch_bounds__(256, 4) void router_gemm(
    const float* __restrict__ xg, const float* __restrict__ wg,
    float* __restrict__ logits) {
  __shared__ __align__(16) float xs[BK][BM + 4];  // transposed x tile (stride 132, 16B-aligned)
  __shared__ __align__(16) float wsm[BK][E];      // transposed W tile

  const int t = threadIdx.x;
  const int bm = blockIdx.x & (ROWBLOCKS - 1);
  const int sp = blockIdx.x >> 7;  // k-split 0..7
  const int row0 = bm * BM;
  const int k0 = sp * KC;

  const int tx = t & 15;  // expert group (4 experts)
  const int ty = t >> 4;  // row group (8 rows)

  // global staging: 8 lanes x 16B cover one row-chunk of 32 floats
  const int lrow = t >> 3;       // 0..31
  const int lcol = (t & 7) * 4;  // 0..28

  const float* xp = xg + (size_t)(row0 + lrow) * D + k0 + lcol;
  const float* wp = wg + (size_t)lrow * D + k0 + lcol;

  float4 xa[4];
  float4 wa[2];

  auto load_tile = [&](int kt) {
#pragma unroll
    for (int i = 0; i < 4; ++i)
      xa[i] = *(const float4*)(xp + (size_t)(i * 32) * D + kt);
#pragma unroll
    for (int i = 0; i < 2; ++i)
      wa[i] = *(const float4*)(wp + (size_t)(i * 32) * D + kt);
  };

  float acc[8][4];
#pragma unroll
  for (int i = 0; i < 8; ++i)
#pragma unroll
    for (int j = 0; j < 4; ++j) acc[i][j] = 0.f;

  load_tile(0);
  for (int tile = 0; tile < NT; ++tile) {
    __syncthreads();
    // scatter staged regs into transposed LDS tiles (4/8-way conflicts ~3% — measured, acceptable)
#pragma unroll
    for (int i = 0; i < 4; ++i) {
      const int r = lrow + i * 32;
      xs[lcol + 0][r] = xa[i].x;
      xs[lcol + 1][r] = xa[i].y;
      xs[lcol + 2][r] = xa[i].z;
      xs[lcol + 3][r] = xa[i].w;
    }
#pragma unroll
    for (int i = 0; i < 2; ++i) {
      const int e = lrow + i * 32;
      wsm[lcol + 0][e] = wa[i].x;
      wsm[lcol + 1][e] = wa[i].y;
      wsm[lcol + 2][e] = wa[i].z;
      wsm[lcol + 3][e] = wa[i].w;
    }
    __syncthreads();
    if (tile + 1 < NT) load_tile((tile + 1) * BK);  // global prefetch overlaps compute

    // rolling fragment registers: k+1 LDS reads issued before k's FMAs retire
    float4 a0 = *(const float4*)&xs[0][ty * 8];
    float4 a1 = *(const float4*)&xs[0][ty * 8 + 4];
    float4 b = *(const float4*)&wsm[0][tx * 4];
#pragma unroll
    for (int k = 0; k < BK; ++k) {
      float4 na0, na1, nb;
      if (k + 1 < BK) {
        na0 = *(const float4*)&xs[k + 1][ty * 8];
        na1 = *(const float4*)&xs[k + 1][ty * 8 + 4];
        nb = *(const float4*)&wsm[k + 1][tx * 4];
      }
      const float av[8] = {a0.x, a0.y, a0.z, a0.w, a1.x, a1.y, a1.z, a1.w};
      const float bv[4] = {b.x, b.y, b.z, b.w};
#pragma unroll
      for (int i = 0; i < 8; ++i)
#pragma unroll
        for (int j = 0; j < 4; ++j) acc[i][j] = fmaf(av[i], bv[j], acc[i][j]);
      if (k + 1 < BK) { a0 = na0; a1 = na1; b = nb; }
    }
  }

  // accumulate K-split partials (8 contributions per address, fp32 atomics)
#pragma unroll
  for (int i = 0; i < 8; ++i) {
    const int r = row0 + ty * 8 + i;
#pragma unroll
    for (int j = 0; j < 4; ++j)
      atomicAdd(&logits[(size_t)r * E + tx * 4 + j], acc[i][j]);
  }
}

// ---------------------------------------------------------------------------
// Kernel 2: thread-per-row epilogue. 256 blocks x 64 threads (1 wave),
// 64 rows/block. LDS transpose (stride 65 = 2-way free), serial row scans
// in each lane — NO cross-lane shuffles in the row loop.
// ---------------------------------------------------------------------------
__global__ __launch_bounds__(64) void router_epilogue(
    const float* __restrict__ logits, float* __restrict__ out) {
  __shared__ float lds[64][65];
  __shared__ int cnt[64];

  const int l = threadIdx.x;  // lane 0..63 = my row within the block
  const int r0 = blockIdx.x * 64;
  cnt[l] = 0;

  // stage 64 rows x 64 cols, coalesced float4 reads, 2-way (free) LDS writes
#pragma unroll
  for (int rr = 0; rr < 16; ++rr) {
    const int row = rr * 4 + (l >> 4);
    const int c4 = (l & 15) * 4;
    const float4 v = *(const float4*)&logits[(size_t)(r0 + row) * 64 + c4];
    lds[row][c4 + 0] = v.x;
    lds[row][c4 + 1] = v.y;
    lds[row][c4 + 2] = v.z;
    lds[row][c4 + 3] = v.w;
  }
  __syncthreads();

  // pass 1: max + top-2 (lower index wins ties, matching lax.top_k)
  float v1 = -3.402823466e+38f, v2 = -3.402823466e+38f;
  int i1 = 0, i2 = 0;
#pragma unroll 8
  for (int e = 0; e < 64; ++e) {
    const float x = lds[l][e];
    if (x > v1) {
      v2 = v1; i2 = i1; v1 = x; i1 = e;
    } else if (x > v2) {
      v2 = x; i2 = e;
    }
  }

  // pass 2: sum of exp(x - max)
  float s = 0.f;
#pragma unroll 8
  for (int e = 0; e < 64; ++e) s += __expf(lds[l][e] - v1);
  const float z = v1 + __logf(s);
  const float rs = 1.f / s;

  const int r = r0 + l;
  out[OFF_IDX + 2 * r] = (float)i1;
  out[OFF_IDX + 2 * r + 1] = (float)i2;
  const float e1 = __expf(v2 - v1);  // v2 <= v1, stable
  const float s0 = 1.f / (1.f + e1);
  out[OFF_SCORES + 2 * r] = s0;
  out[OFF_SCORES + 2 * r + 1] = e1 * s0;
  atomicAdd(&cnt[i1], 1);
  atomicAdd(&cnt[i2], 1);

  // pass 3: probs in-place (lane owns row l)
#pragma unroll 8
  for (int e = 0; e < 64; ++e) lds[l][e] = __expf(lds[l][e] - v1) * rs;
  __syncthreads();

  // coalesced probs store
#pragma unroll
  for (int rr = 0; rr < 16; ++rr) {
    const int row = rr * 4 + (l >> 4);
    const int c4 = (l & 15) * 4;
    float4 v;
    v.x = lds[row][c4 + 0];
    v.y = lds[row][c4 + 1];
    v.z = lds[row][c4 + 2];
    v.w = lds[row][c4 + 3];
    *(float4*)&out[OFF_PROBS + (size_t)(r0 + row) * 64 + c4] = v;
  }

  // importance: lane e sums column e over the block's 64 rows (conflict-free)
  float ic = 0.f;
#pragma unroll 8
  for (int rr = 0; rr < 64; ++rr) ic += lds[rr][l];
  atomicAdd(&out[OFF_IMP + l], ic * (1.f / 16384.f));

  // load: exact integer counts -> k/32768 exactly representable, order-safe
  atomicAdd(&out[OFF_LOAD + l], (float)cnt[l] * (1.f / 32768.f));

  // z-loss: one value per lane, wave butterfly, single atomic
  float zz = z * z;
#pragma unroll
  for (int off = 32; off > 0; off >>= 1) zz += __shfl_xor(zz, off);
  if (l == 0) atomicAdd(&out[OFF_Z], zz * (1.f / 16384.f) * (1.f / 64.f) * 64.f);
}

extern "C" void kernel_launch(void* const* d_in, const int* in_sizes, int n_in,
                              void* d_out, int out_size, void* d_ws, size_t ws_size,
                              hipStream_t stream) {
  const float* x = (const float*)d_in[0];
  const float* wgate = (const float*)d_in[1];
  float* out = (float*)d_out;
  float* logits = (float*)d_ws;  // 16384*64 fp32 = 4 MB scratch

  // zero the atomic-accumulated regions (ws + stats tail of d_out are poisoned)
  hipMemsetAsync(logits, 0, (size_t)M * E * sizeof(float), stream);
  hipMemsetAsync(out + OFF_Z, 0, 129 * sizeof(float), stream);

  router_gemm<<<dim3(ROWBLOCKS * KSPLIT), dim3(256), 0, stream>>>(x, wgate, logits);
  router_epilogue<<<dim3(M / 64), dim3(64), 0, stream>>>(logits, out);
}

// Round 3
// 408.976 us; speedup vs baseline: 1.3317x; 1.1341x over previous
//
#include <hip/hip_runtime.h>

namespace {
constexpr int D = 4096;   // d_model
constexpr int E = 64;     // n_experts
constexpr int M = 16384;  // B*S
constexpr int BM = 64;    // rows per block
constexpr int BK = 64;    // k per round
constexpr int NT = D / BK;      // 64 rounds
constexpr int NBLK = M / BM;    // 256 blocks

// output layout (floats, concatenated in reference return order)
constexpr int OFF_IDX = 0;         // [M][2]
constexpr int OFF_SCORES = 32768;  // [M][2]
constexpr int OFF_PROBS = 65536;   // [M][64]
constexpr int OFF_Z = 1114112;     // scalar
constexpr int OFF_IMP = 1114113;   // [64]
constexpr int OFF_LOAD = 1114177;  // [64]

constexpr int WS_STRIDE = 132;  // per-block stats: 64 imp | 64 cnt | 1 z2
}  // namespace

// ---------------------------------------------------------------------------
// Fused router: GEMM (full-K per block, 4 k-slices in-block) + epilogue.
// 256 blocks x 512 threads. LDS 64 KB: double-buffered k-major tiles
// Xs[k][64 rows], Ws[k][64 experts], XOR-(k>>4) swizzled so staging writes
// and fragment reads are both <=2-way (free). One barrier per round.
// ---------------------------------------------------------------------------
__global__ __launch_bounds__(512, 2) void router_fused(
    const float* __restrict__ xg, const float* __restrict__ wg,
    float* __restrict__ out, float* __restrict__ ws) {
  __shared__ float smem[16384];  // 64 KB = 2 buffers x (Xs 4096 | Ws 4096)

  const int t = threadIdx.x;
  const int u = t & 127;
  const int s = t >> 7;   // k-slice 0..3
  const int tx = u & 15;  // expert group (4 experts)
  const int ty = u >> 4;  // row group (8 rows)
  const int r0 = blockIdx.x * BM;

  // staging mapping: thread covers (row sr, cols sc & sc+32), 128B segments
  const int sr = t >> 3;        // 0..63 (row of x-tile / expert-row of W)
  const int sc = (t & 7) * 4;   // 0..28
  const float* xp = xg + (size_t)(r0 + sr) * D + sc;
  const float* wp = wg + (size_t)sr * D + sc;

  float4 vx[2], vw[2];

  auto stage_load = [&](int k0) {
    vx[0] = *(const float4*)(xp + k0);
    vx[1] = *(const float4*)(xp + k0 + 32);
    vw[0] = *(const float4*)(wp + k0);
    vw[1] = *(const float4*)(wp + k0 + 32);
  };
  auto stage_write = [&](float* buf) {
    float* Xs = buf;
    float* Ws = buf + 4096;
#pragma unroll
    for (int h = 0; h < 2; ++h) {
      const int c = sc + h * 32;              // tile k-col of this float4
      const int sw = ((c >> 4) & 3) << 3;     // bank swizzle (const per float4)
      const int rp = sr ^ sw;
      Xs[(c + 0) * 64 + rp] = vx[h].x;
      Xs[(c + 1) * 64 + rp] = vx[h].y;
      Xs[(c + 2) * 64 + rp] = vx[h].z;
      Xs[(c + 3) * 64 + rp] = vx[h].w;
      Ws[(c + 0) * 64 + rp] = vw[h].x;
      Ws[(c + 1) * 64 + rp] = vw[h].y;
      Ws[(c + 2) * 64 + rp] = vw[h].z;
      Ws[(c + 3) * 64 + rp] = vw[h].w;
    }
  };

  float acc[8][4];
#pragma unroll
  for (int i = 0; i < 8; ++i)
#pragma unroll
    for (int j = 0; j < 4; ++j) acc[i][j] = 0.f;

  // slice s reads kp in [s*16, s*16+16) each round -> (kp>>4)==s (const swizzle)
  const int rbx = (ty * 8) ^ (s << 3);
  const int rbw = (tx * 4) ^ (s << 3);

  stage_load(0);
  stage_write(smem);  // buffer 0

  for (int r = 0; r < NT; ++r) {
    __syncthreads();  // tile r ready; all waves done with tile r-1's buffer
    if (r + 1 < NT) stage_load((r + 1) * BK);  // global loads fly over compute

    const float* buf = smem + (r & 1) * 8192;
    const float* Xs = buf + (size_t)(s * 16) * 64;  // slice base: offsets become imms
    const float* Ws = buf + 4096 + (size_t)(s * 16) * 64;
#pragma unroll
    for (int kk = 0; kk < 16; ++kk) {
      const float4 a0 = *(const float4*)&Xs[kk * 64 + rbx];
      const float4 a1 = *(const float4*)&Xs[kk * 64 + rbx + 4];
      const float4 bw = *(const float4*)&Ws[kk * 64 + rbw];
      const float av[8] = {a0.x, a0.y, a0.z, a0.w, a1.x, a1.y, a1.z, a1.w};
      const float bv[4] = {bw.x, bw.y, bw.z, bw.w};
#pragma unroll
      for (int i = 0; i < 8; ++i)
#pragma unroll
        for (int j = 0; j < 4; ++j) acc[i][j] = fmaf(av[i], bv[j], acc[i][j]);
    }
    if (r + 1 < NT) stage_write(smem + ((r + 1) & 1) * 8192);  // other buffer: safe
  }

  // ---- in-block k-slice reduction (2 phases to fit 64 KB) ----
  float* P = smem;  // [2][128][33] = 8448 floats
  __syncthreads();
  if (s >= 2) {
    float* p = P + ((size_t)((s - 2) * 128 + u)) * 33;
#pragma unroll
    for (int i = 0; i < 8; ++i)
#pragma unroll
      for (int j = 0; j < 4; ++j) p[i * 4 + j] = acc[i][j];
  }
  __syncthreads();
  if (s < 2) {
    const float* p = P + ((size_t)(s * 128 + u)) * 33;
#pragma unroll
    for (int i = 0; i < 8; ++i)
#pragma unroll
      for (int j = 0; j < 4; ++j) acc[i][j] += p[i * 4 + j];
  }
  __syncthreads();
  if (s == 1) {
    float* p = P + (size_t)u * 33;
#pragma unroll
    for (int i = 0; i < 8; ++i)
#pragma unroll
      for (int j = 0; j < 4; ++j) p[i * 4 + j] = acc[i][j];
  }
  __syncthreads();

  // epilogue LDS regions (P region dead after the final add below)
  float* Lg = smem + 8448;        // [64][65] logits
  float* rowmax = smem + 12608;   // [64]
  float* rowrs = rowmax + 64;     // [64]
  float* zrow = rowrs + 64;       // [64]
  int* cnt = (int*)(zrow + 64);   // [64]

  if (s == 0) {
    const float* p = P + (size_t)u * 33;
#pragma unroll
    for (int i = 0; i < 8; ++i)
#pragma unroll
      for (int j = 0; j < 4; ++j) {
        const float v = acc[i][j] + p[i * 4 + j];
        Lg[(ty * 8 + i) * 65 + tx * 4 + j] = v;
      }
  }
  if (t < 64) cnt[t] = 0;
  __syncthreads();

  // per-row scan: top-2 (lower index wins ties, matching lax.top_k) + lse
  if (t < 64) {
    const float* row = Lg + t * 65;
    float v1 = -3.402823466e+38f, v2 = -3.402823466e+38f;
    int i1 = 0, i2 = 0;
#pragma unroll 8
    for (int e = 0; e < 64; ++e) {
      const float x = row[e];
      if (x > v1) {
        v2 = v1; i2 = i1; v1 = x; i1 = e;
      } else if (x > v2) {
        v2 = x; i2 = e;
      }
    }
    float ssum = 0.f;
#pragma unroll 8
    for (int e = 0; e < 64; ++e) ssum += __expf(row[e] - v1);
    const float z = v1 + __logf(ssum);
    rowmax[t] = v1;
    rowrs[t] = 1.f / ssum;
    zrow[t] = z * z;

    const int r = r0 + t;
    out[OFF_IDX + 2 * r] = (float)i1;
    out[OFF_IDX + 2 * r + 1] = (float)i2;
    const float e1 = __expf(v2 - v1);  // v2 <= v1, stable
    const float s0 = 1.f / (1.f + e1);
    out[OFF_SCORES + 2 * r] = s0;
    out[OFF_SCORES + 2 * r + 1] = e1 * s0;
    atomicAdd(&cnt[i1], 1);
    atomicAdd(&cnt[i2], 1);
  }
  __syncthreads();

  // probs: all 512 threads, 8 elements each; overwrite Lg for column sums
  {
    const int pr = t >> 3;
    const int pc = (t & 7) * 8;
    float* prow = Lg + pr * 65 + pc;
    const float m = rowmax[pr];
    const float rs = rowrs[pr];
    float p[8];
#pragma unroll
    for (int q = 0; q < 8; ++q) p[q] = __expf(prow[q] - m) * rs;
    float4 o0 = {p[0], p[1], p[2], p[3]};
    float4 o1 = {p[4], p[5], p[6], p[7]};
    *(float4*)&out[OFF_PROBS + (size_t)(r0 + pr) * 64 + pc] = o0;
    *(float4*)&out[OFF_PROBS + (size_t)(r0 + pr) * 64 + pc + 4] = o1;
#pragma unroll
    for (int q = 0; q < 8; ++q) prow[q] = p[q];
  }
  __syncthreads();

  // per-block stats -> ws (no global atomics; tiny reduce kernel finishes)
  if (t < 64) {
    float ic = 0.f;
#pragma unroll 8
    for (int rr = 0; rr < 64; ++rr) ic += Lg[rr * 65 + t];
    ws[(size_t)blockIdx.x * WS_STRIDE + t] = ic;
    ws[(size_t)blockIdx.x * WS_STRIDE + 64 + t] = (float)cnt[t];
    float zz = zrow[t];
#pragma unroll
    for (int off = 32; off > 0; off >>= 1) zz += __shfl_xor(zz, off);
    if (t == 0) ws[(size_t)blockIdx.x * WS_STRIDE + 128] = zz;
  }
}

// ---------------------------------------------------------------------------
// Final reduction over 256 per-block stat slots.
// ---------------------------------------------------------------------------
__global__ __launch_bounds__(192) void router_reduce(
    const float* __restrict__ ws, float* __restrict__ out) {
  const int t = threadIdx.x;
  if (t < 129) {
    float v = 0.f;
#pragma unroll 8
    for (int b = 0; b < NBLK; ++b) v += ws[(size_t)b * WS_STRIDE + t];
    if (t < 64)
      out[OFF_IMP + t] = v * (1.f / 16384.f);
    else if (t < 128)
      // counts are integers; /32768 exact; denominator max(sum,1)=32768
      out[OFF_LOAD + (t - 64)] = v * (1.f / 32768.f);
    else
      out[OFF_Z] = v * (1.f / 16384.f);
  }
}

extern "C" void kernel_launch(void* const* d_in, const int* in_sizes, int n_in,
                              void* d_out, int out_size, void* d_ws, size_t ws_size,
                              hipStream_t stream) {
  const float* x = (const float*)d_in[0];
  const float* wgate = (const float*)d_in[1];
  float* out = (float*)d_out;
  float* ws = (float*)d_ws;  // 256*132 floats = 132 KB, fully written each call

  router_fused<<<dim3(NBLK), dim3(512), 0, stream>>>(x, wgate, out, ws);
  router_reduce<<<dim3(1), dim3(192), 0, stream>>>(ws, out);
}